// Round 1
// 450.593 us; speedup vs baseline: 1.0192x; 1.0192x over previous
//
#include <hip/hip_runtime.h>
#include <hip/hip_bf16.h>

typedef __hip_bfloat16 bf16;
typedef __attribute__((ext_vector_type(8))) short bf16x8;  // 8 bf16 = 4 VGPRs (MFMA A/B frag)
typedef __attribute__((ext_vector_type(4))) short bf16x4;  // 4 bf16 = 8B packed store
typedef __attribute__((ext_vector_type(4))) float f32x4;   // MFMA C/D frag

#define D_MODEL 2048
#define SEQ     2048
#define NH      16
#define DH      128
#define BATCH   2
#define MTOT    (BATCH*SEQ)   // 4096

__device__ __forceinline__ void async_cp16(const bf16* g, bf16* l) {
    // wave-uniform LDS base; HW scatters lane i at base + i*16B
    __builtin_amdgcn_global_load_lds(
        (const __attribute__((address_space(1))) void*)g,
        (__attribute__((address_space(3))) void*)l, 16, 0, 0);
}

__device__ __forceinline__ short bf16bits(float f) {
    bf16 b = __float2bfloat16(f);
    return *reinterpret_cast<short*>(&b);
}

// ---------------- f32 -> bf16 elementwise convert (8 elems/thread) ----------------
__global__ __launch_bounds__(256) void cvt_k(const float* __restrict__ in,
                                             bf16* __restrict__ out) {
    const long i = ((long)blockIdx.x * 256 + threadIdx.x) * 8;
    float4 a = *(const float4*)(in + i);
    float4 b = *(const float4*)(in + i + 4);
    __align__(16) bf16 t[8];
    t[0] = __float2bfloat16(a.x); t[1] = __float2bfloat16(a.y);
    t[2] = __float2bfloat16(a.z); t[3] = __float2bfloat16(a.w);
    t[4] = __float2bfloat16(b.x); t[5] = __float2bfloat16(b.y);
    t[6] = __float2bfloat16(b.z); t[7] = __float2bfloat16(b.w);
    *(bf16x8*)(out + i) = *(const bf16x8*)t;
}

// ---- f32 [mat][R][Cn] -> bf16 [mat][Cn][R] transpose-convert; 3-src variant for QKV ----
__global__ __launch_bounds__(256) void transpose_cvt3_k(
    const float* __restrict__ in0, const float* __restrict__ in1,
    const float* __restrict__ in2,
    bf16* __restrict__ out, int R, int Cn, int mats_per_src)
{
    __shared__ float t[32][33];
    const int z = blockIdx.z;
    const int src = z / mats_per_src, mat = z % mats_per_src;
    const float* in = (src == 0) ? in0 : (src == 1) ? in1 : in2;
    const float* inm = in + (long)mat * R * Cn;
    bf16* outm = out + (long)z * R * Cn;
    const int c0 = blockIdx.x * 32, r0 = blockIdx.y * 32;
    const int tx = threadIdx.x & 31, ty = threadIdx.x >> 5;   // ty 0..7
#pragma unroll
    for (int i = 0; i < 4; ++i)
        t[ty + i*8][tx] = inm[(long)(r0 + ty + i*8) * Cn + c0 + tx];
    __syncthreads();
#pragma unroll
    for (int i = 0; i < 4; ++i)
        outm[(long)(c0 + ty + i*8) * R + r0 + tx] = __float2bfloat16(t[tx][ty + i*8]);
}

// ---------------- per-head V transpose: [b][key][h*DH+f] -> [(b,h)][f][key] bf16 ----------------
__global__ __launch_bounds__(256) void transpose_v_k(
    const bf16* __restrict__ V, bf16* __restrict__ VT)
{
    __shared__ bf16 t[32][33];
    const int bh = blockIdx.z;              // b*NH + h
    const int b = bh >> 4, h = bh & 15;
    const bf16* inm = V + (long)b*SEQ*D_MODEL + h*DH;       // [key][f] stride D_MODEL
    bf16* outm = VT + (long)bh*DH*SEQ;                      // [f][key] stride SEQ
    const int r0 = blockIdx.x * 32;         // key tile
    const int c0 = blockIdx.y * 32;         // feat tile
    const int tx = threadIdx.x & 31, ty = threadIdx.x >> 5;
#pragma unroll
    for (int i = 0; i < 4; ++i)
        t[ty + i*8][tx] = inm[(long)(r0 + ty + i*8)*D_MODEL + c0 + tx];
    __syncthreads();
#pragma unroll
    for (int i = 0; i < 4; ++i)
        outm[(long)(c0 + ty + i*8)*SEQ + r0 + tx] = t[tx][ty + i*8];
}

// ---------------- 128x128 tile GEMM: C = A[M,K] * Bt[N,K]^T + bias ----------------
template <bool C_F32>
__device__ __forceinline__ void gemm128x128(
    const bf16* __restrict__ A, int lda,
    const bf16* __restrict__ Bt, int ldb,
    void* __restrict__ C, int ldc,
    const float* __restrict__ bias,
    int Kdim, int m0, int n0)
{
    __shared__ __align__(16) bf16 As[128*32];
    __shared__ __align__(16) bf16 Bs[128*32];
    const int tid  = threadIdx.x;
    const int wave = tid >> 6, lane = tid & 63;
    const int lr = lane & 15, lq = lane >> 4;
    const int wrow = wave >> 1, wcol = wave & 1;
    const int sr = lane >> 2, sk = (lane & 3) * 8;

    const f32x4 zero4 = {0.f, 0.f, 0.f, 0.f};
    f32x4 acc[4][4];
#pragma unroll
    for (int i = 0; i < 4; ++i)
#pragma unroll
        for (int j = 0; j < 4; ++j) acc[i][j] = zero4;

    for (int k0 = 0; k0 < Kdim; k0 += 32) {
#pragma unroll
        for (int c = 0; c < 2; ++c) {
            const int r = wave*32 + c*16;
            async_cp16(A  + (long)(m0 + r + sr)*lda + k0 + sk, As + r*32);
            async_cp16(Bt + (long)(n0 + r + sr)*ldb + k0 + sk, Bs + r*32);
        }
        __syncthreads();
        bf16x8 af[4], bfr[4];
#pragma unroll
        for (int i = 0; i < 4; ++i)
            af[i] = *(const bf16x8*)(As + (wrow*64 + i*16 + lr)*32 + lq*8);
#pragma unroll
        for (int j = 0; j < 4; ++j)
            bfr[j] = *(const bf16x8*)(Bs + (wcol*64 + j*16 + lr)*32 + lq*8);
#pragma unroll
        for (int i = 0; i < 4; ++i)
#pragma unroll
            for (int j = 0; j < 4; ++j)
                acc[i][j] = __builtin_amdgcn_mfma_f32_16x16x32_bf16(af[i], bfr[j], acc[i][j], 0, 0, 0);
        __syncthreads();
    }
#pragma unroll
    for (int j = 0; j < 4; ++j) {
        const int col = n0 + wcol*64 + j*16 + lr;
        const float bv = bias[col];
#pragma unroll
        for (int i = 0; i < 4; ++i) {
            const int row = m0 + wrow*64 + i*16 + lq*4;
#pragma unroll
            for (int r = 0; r < 4; ++r) {
                const float v = acc[i][j][r] + bv;
                if constexpr (C_F32) ((float*)C)[(long)(row + r)*ldc + col] = v;
                else ((bf16*)C)[(long)(row + r)*ldc + col] = __float2bfloat16(v);
            }
        }
    }
}

// ---------------- QKV projection ----------------
__global__ __launch_bounds__(256) void qkv_gemm_k(
    const bf16* __restrict__ X, const bf16* __restrict__ WT3,
    const float* __restrict__ bQ, const float* __restrict__ bK, const float* __restrict__ bV,
    bf16* __restrict__ Qo, bf16* __restrict__ Ko, bf16* __restrict__ Vo)
{
    const int mt  = blockIdx.x;        // 0..31
    const int sel = blockIdx.y >> 4;   // 0=Q 1=K 2=V
    const int h   = blockIdx.y & 15;
    const float* bias; bf16* C;
    if (sel == 0)      { bias = bQ; C = Qo; }
    else if (sel == 1) { bias = bK; C = Ko; }
    else               { bias = bV; C = Vo; }
    gemm128x128<false>(X, D_MODEL, WT3 + (long)blockIdx.y*DH*D_MODEL, D_MODEL,
                       C + h*DH, NH*DH, bias + h*DH, D_MODEL, mt*128, 0);
}

// ---------------- output projection (f32 out + f32 bias) ----------------
__global__ __launch_bounds__(256) void out_gemm_k(
    const bf16* __restrict__ Z, const bf16* __restrict__ WOT,
    const float* __restrict__ bO, float* __restrict__ Out)
{
    gemm128x128<true>(Z, D_MODEL, WOT, D_MODEL, Out, D_MODEL, bO, D_MODEL,
                      (int)blockIdx.x*128, (int)blockIdx.y*128);
}

// ---------------- flash attention: S^T = K Q^T, O^T = V^T P^T ----------------
// K tile: Ks[key][128feat], 256B rows, 16B-slot XOR swizzle (slot ^= key&7).
// V tile: Vts[feat][64key], 128B rows, 16B-slot XOR swizzle (slot ^= feat&7).
// Swizzle applied on the per-lane GLOBAL source address (global_load_lds writes
// linearly — rule #21: both-sides-or-neither), and on the ds_read address.
// After swizzle every 16-lane phase group covers 8 start-banks x 2 = 2-way (free).
__global__ __launch_bounds__(256) void flash_k(
    const bf16* __restrict__ Q, const bf16* __restrict__ K,
    const bf16* __restrict__ VT, bf16* __restrict__ Z)
{
    __shared__ __align__(16) bf16 Ks[64*128];    // [key][feat] swizzled   16KB
    __shared__ __align__(16) bf16 Vts[128*64];   // [feat][key] swizzled   16KB
    __shared__ __align__(16) bf16 Ps[64*72];     // [qrow][key] pad 72      9KB

    const int qt = (int)(gridDim.x - 1) - (int)blockIdx.x;   // big tiles dispatch first
    const int bh = blockIdx.y;
    const int b  = bh >> 4, h = bh & 15;
    const long base = (long)b*SEQ*D_MODEL + h*DH;
    const bf16* Qb  = Q + base;
    const bf16* Kb  = K + base;
    const bf16* VTb = VT + (long)bh*DH*SEQ;      // [feat][key] stride SEQ
    bf16* Zb = Z + base;
    const int q0 = qt*64;
    const int tid = threadIdx.x, wave = tid >> 6, lane = tid & 63;
    const int lr = lane & 15, lq = lane >> 4;
    const int rx = lr & 7;                        // read-side swizzle key (row&7)

    // staging geometry (wave-uniform LDS base, per-lane swizzled global src)
    const int ks_key_off = lane >> 4;             // key within 4-row chunk
    const int ks_slot    = lane & 15;             // 16B slot within 256B row
    const int vt_row_off = lane >> 3;             // feat within 8-row chunk
    const int vt_slot    = lane & 7;              // 16B slot within 128B row

    // Q B-frags in registers: lane holds q-row (q0+wave*16+lr), feats ks*32+lq*8..+8
    bf16x8 aq[4];
#pragma unroll
    for (int ks = 0; ks < 4; ++ks)
        aq[ks] = *(const bf16x8*)(Qb + (long)(q0 + wave*16 + lr)*D_MODEL + ks*32 + lq*8);

    const f32x4 zero4 = {0.f, 0.f, 0.f, 0.f};
    f32x4 o_acc[8];           // O^T: col=qrow(lr), row=feat(jf*16+lq*4+r)
#pragma unroll
    for (int jf = 0; jf < 8; ++jf) o_acc[jf] = zero4;
    float m_run = -1e30f, l_run = 0.f;   // per-lane (qrow=lr), scaled domain

    const float scale = 0.08838834764831845f;  // 1/sqrt(128)

    for (int kt = 0; kt <= qt; ++kt) {
        const int k0 = kt*64;
        __syncthreads();   // all waves done reading Ks/Vts of prev tile
        // K: wave stages keys wave*16 .. +15 (4 cps x 4 keys of 256B)
#pragma unroll
        for (int c = 0; c < 4; ++c) {
            const int key = (wave*4 + c)*4 + ks_key_off;
            async_cp16(Kb + (long)(k0 + key)*D_MODEL + ((ks_slot ^ (key & 7)) * 8),
                       Ks + (wave*4 + c)*512);
        }
        // V^T: wave stages feats wave*32 .. +31 (4 cps x 8 rows of 128B)
#pragma unroll
        for (int c = 0; c < 4; ++c) {
            const int f = (wave*4 + c)*8 + vt_row_off;
            async_cp16(VTb + (long)f*SEQ + k0 + ((vt_slot ^ (f & 7)) * 8),
                       Vts + (wave*4 + c)*512);
        }
        __syncthreads();

        // S^T = K Q^T: sc[mt] C-frag: col=qrow(lr), row=key(mt*16+lq*4+r)
        f32x4 sc[4];
#pragma unroll
        for (int mt = 0; mt < 4; ++mt) sc[mt] = zero4;
        __builtin_amdgcn_s_setprio(1);
#pragma unroll
        for (int mt = 0; mt < 4; ++mt)
#pragma unroll
            for (int ks = 0; ks < 4; ++ks) {
                // logical slot = ks*4+lq, physical = slot ^ (key&7); key&7 == lr&7
                bf16x8 bk = *(const bf16x8*)(Ks + (mt*16 + lr)*128 + (((ks*4 + lq) ^ rx) * 8));
                sc[mt] = __builtin_amdgcn_mfma_f32_16x16x32_bf16(bk, aq[ks], sc[mt], 0, 0, 0);
            }
        __builtin_amdgcn_s_setprio(0);

        // causal mask: only the diagonal tile is partial
        if (kt == qt) {
            const int qrl = wave*16 + lr;   // lane's q-row within the 64-tile (q0==k0)
#pragma unroll
            for (int mt = 0; mt < 4; ++mt)
#pragma unroll
                for (int r = 0; r < 4; ++r)
                    if (mt*16 + lq*4 + r > qrl) sc[mt][r] = -1e30f;
        }

        // row max over lane's 16 keys, then across lq groups (xor 16,32)
        float mx = sc[0][0];
#pragma unroll
        for (int mt = 0; mt < 4; ++mt)
#pragma unroll
            for (int r = 0; r < 4; ++r) mx = fmaxf(mx, sc[mt][r]);
        mx = fmaxf(mx, __shfl_xor(mx, 16, 64));
        mx = fmaxf(mx, __shfl_xor(mx, 32, 64));
        mx *= scale;   // scaled domain

        // T13 defer-max: skip the O-rescale while max growth <= 8 (P bounded by e^8)
        if (!__all(mx - m_run <= 8.0f)) {
            const float mn = fmaxf(m_run, mx);
            const float al = __expf(m_run - mn);
            l_run *= al;
#pragma unroll
            for (int jf = 0; jf < 8; ++jf)
#pragma unroll
                for (int r = 0; r < 4; ++r) o_acc[jf][r] *= al;
            m_run = mn;
        }

        float rs = 0.f;
#pragma unroll
        for (int mt = 0; mt < 4; ++mt)
#pragma unroll
            for (int r = 0; r < 4; ++r) {
                const float p = __expf(fmaf(sc[mt][r], scale, -m_run));
                sc[mt][r] = p;
                rs += p;
            }
        rs += __shfl_xor(rs, 16, 64);
        rs += __shfl_xor(rs, 32, 64);
        l_run += rs;

        // P^T: C-frag (qrow=lr, key=mt*16+lq*4+r) -> Ps[qrow][key] -> contiguous B-frag
        // rows are wave-private (qrow = wave*16+lr); same-wave write->read, no barrier
        // packed 8B stores: 4 ds_write_b64 instead of 16 ds_write_b16
#pragma unroll
        for (int mt = 0; mt < 4; ++mt) {
            bf16x4 pk;
#pragma unroll
            for (int r = 0; r < 4; ++r) pk[r] = bf16bits(sc[mt][r]);
            *(bf16x4*)(Ps + (wave*16 + lr)*72 + mt*16 + lq*4) = pk;
        }

        bf16x8 pb0 = *(const bf16x8*)(Ps + (wave*16 + lr)*72 + lq*8);
        bf16x8 pb1 = *(const bf16x8*)(Ps + (wave*16 + lr)*72 + 32 + lq*8);

        // O^T += V^T P^T
        __builtin_amdgcn_s_setprio(1);
#pragma unroll
        for (int jf = 0; jf < 8; ++jf) {
            const int f = jf*16 + lr;
            bf16x8 av0 = *(const bf16x8*)(Vts + f*64 + ((lq ^ rx) * 8));
            bf16x8 av1 = *(const bf16x8*)(Vts + f*64 + (((4 + lq) ^ rx) * 8));
            o_acc[jf] = __builtin_amdgcn_mfma_f32_16x16x32_bf16(av0, pb0, o_acc[jf], 0, 0, 0);
            o_acc[jf] = __builtin_amdgcn_mfma_f32_16x16x32_bf16(av1, pb1, o_acc[jf], 0, 0, 0);
        }
        __builtin_amdgcn_s_setprio(0);
    }

    const float inv = 1.f / l_run;
    const long zrow = (long)(q0 + wave*16 + lr) * D_MODEL;
#pragma unroll
    for (int jf = 0; jf < 8; ++jf) {
        bf16x4 pk;
#pragma unroll
        for (int r = 0; r < 4; ++r) pk[r] = bf16bits(o_acc[jf][r] * inv);
        *(bf16x4*)(Zb + zrow + jf*16 + lq*4) = pk;
    }
}

extern "C" void kernel_launch(void* const* d_in, const int* in_sizes, int n_in,
                              void* d_out, int out_size, void* d_ws, size_t ws_size,
                              hipStream_t stream) {
    const float* X  = (const float*)d_in[0];
    const float* WQ = (const float*)d_in[1];   // [NH][D_MODEL][DH] f32
    const float* WK = (const float*)d_in[2];
    const float* WV = (const float*)d_in[3];
    const float* WO = (const float*)d_in[4];   // flat [2048][2048] f32
    const float* bQ = (const float*)d_in[5];
    const float* bK = (const float*)d_in[6];
    const float* bV = (const float*)d_in[7];
    const float* bO = (const float*)d_in[8];
    float* out = (float*)d_out;

    bf16* ws = (bf16*)d_ws;
    const long WSZ = (long)NH*DH*D_MODEL;   // 4,194,304 elems (8 MiB bf16)
    const long MSZ = (long)MTOT*D_MODEL;    // 8,388,608 elems (16 MiB bf16)
    bf16* Xb  = ws;
    bf16* WT3 = Xb + MSZ;        // 3*WSZ: transposed QKV weights [48][DH][D_MODEL]
    bf16* WOT = WT3 + 3*WSZ;
    bf16* Qb  = WOT + WSZ;
    bf16* Kb  = Qb + MSZ;
    bf16* Vb  = Kb + MSZ;
    bf16* Zb  = Xb;              // alias: X dead after QKV GEMM
    bf16* VT  = WT3;             // alias: QKV weight transposes dead after QKV GEMM
    // ws use: MSZ + 4*WSZ + 3*MSZ = 96 MiB

    cvt_k<<<MSZ/(256*8), 256, 0, stream>>>(X, Xb);
    transpose_cvt3_k<<<dim3(DH/32, D_MODEL/32, 3*NH), 256, 0, stream>>>(
        WQ, WK, WV, WT3, D_MODEL, DH, NH);
    transpose_cvt3_k<<<dim3(D_MODEL/32, D_MODEL/32, 1), 256, 0, stream>>>(
        WO, WO, WO, WOT, D_MODEL, D_MODEL, 1);

    qkv_gemm_k<<<dim3(MTOT/128, 48), 256, 0, stream>>>(Xb, WT3, bQ, bK, bV, Qb, Kb, Vb);
    transpose_v_k<<<dim3(SEQ/32, DH/32, BATCH*NH), 256, 0, stream>>>(Vb, VT);
    flash_k<<<dim3(SEQ/64, BATCH*NH), 256, 0, stream>>>(Qb, Kb, VT, Zb);
    out_gemm_k<<<dim3(MTOT/128, D_MODEL/128), 256, 0, stream>>>(Zb, WOT, bO, out);
}

// Round 2
// 441.271 us; speedup vs baseline: 1.0407x; 1.0211x over previous
//
#include <hip/hip_runtime.h>
#include <hip/hip_bf16.h>

typedef __hip_bfloat16 bf16;
typedef __attribute__((ext_vector_type(8))) short bf16x8;  // 8 bf16 = 4 VGPRs (MFMA A/B frag)
typedef __attribute__((ext_vector_type(4))) short bf16x4;  // 4 bf16 = 8B packed store
typedef __attribute__((ext_vector_type(4))) float f32x4;   // MFMA C/D frag

#define D_MODEL 2048
#define SEQ     2048
#define NH      16
#define DH      128
#define BATCH   2
#define MTOT    (BATCH*SEQ)   // 4096

__device__ __forceinline__ void async_cp16(const bf16* g, bf16* l) {
    // wave-uniform LDS base; HW scatters lane i at base + i*16B
    __builtin_amdgcn_global_load_lds(
        (const __attribute__((address_space(1))) void*)g,
        (__attribute__((address_space(3))) void*)l, 16, 0, 0);
}

__device__ __forceinline__ short bf16bits(float f) {
    bf16 b = __float2bfloat16(f);
    return *reinterpret_cast<short*>(&b);
}

// ---------------- f32 -> bf16 elementwise convert (8 elems/thread) ----------------
__global__ __launch_bounds__(256) void cvt_k(const float* __restrict__ in,
                                             bf16* __restrict__ out) {
    const long i = ((long)blockIdx.x * 256 + threadIdx.x) * 8;
    float4 a = *(const float4*)(in + i);
    float4 b = *(const float4*)(in + i + 4);
    __align__(16) bf16 t[8];
    t[0] = __float2bfloat16(a.x); t[1] = __float2bfloat16(a.y);
    t[2] = __float2bfloat16(a.z); t[3] = __float2bfloat16(a.w);
    t[4] = __float2bfloat16(b.x); t[5] = __float2bfloat16(b.y);
    t[6] = __float2bfloat16(b.z); t[7] = __float2bfloat16(b.w);
    *(bf16x8*)(out + i) = *(const bf16x8*)t;
}

// ---- f32 [mat][R][Cn] -> bf16 [mat][Cn][R] transpose-convert; 3-src variant for QKV ----
__global__ __launch_bounds__(256) void transpose_cvt3_k(
    const float* __restrict__ in0, const float* __restrict__ in1,
    const float* __restrict__ in2,
    bf16* __restrict__ out, int R, int Cn, int mats_per_src)
{
    __shared__ float t[32][33];
    const int z = blockIdx.z;
    const int src = z / mats_per_src, mat = z % mats_per_src;
    const float* in = (src == 0) ? in0 : (src == 1) ? in1 : in2;
    const float* inm = in + (long)mat * R * Cn;
    bf16* outm = out + (long)z * R * Cn;
    const int c0 = blockIdx.x * 32, r0 = blockIdx.y * 32;
    const int tx = threadIdx.x & 31, ty = threadIdx.x >> 5;   // ty 0..7
#pragma unroll
    for (int i = 0; i < 4; ++i)
        t[ty + i*8][tx] = inm[(long)(r0 + ty + i*8) * Cn + c0 + tx];
    __syncthreads();
#pragma unroll
    for (int i = 0; i < 4; ++i)
        outm[(long)(c0 + ty + i*8) * R + r0 + tx] = __float2bfloat16(t[tx][ty + i*8]);
}

// ---------------- per-head V transpose: [b][key][h*DH+f] -> [(b,h)][f][key] bf16 ----------------
__global__ __launch_bounds__(256) void transpose_v_k(
    const bf16* __restrict__ V, bf16* __restrict__ VT)
{
    __shared__ bf16 t[32][33];
    const int bh = blockIdx.z;              // b*NH + h
    const int b = bh >> 4, h = bh & 15;
    const bf16* inm = V + (long)b*SEQ*D_MODEL + h*DH;       // [key][f] stride D_MODEL
    bf16* outm = VT + (long)bh*DH*SEQ;                      // [f][key] stride SEQ
    const int r0 = blockIdx.x * 32;         // key tile
    const int c0 = blockIdx.y * 32;         // feat tile
    const int tx = threadIdx.x & 31, ty = threadIdx.x >> 5;
#pragma unroll
    for (int i = 0; i < 4; ++i)
        t[ty + i*8][tx] = inm[(long)(r0 + ty + i*8)*D_MODEL + c0 + tx];
    __syncthreads();
#pragma unroll
    for (int i = 0; i < 4; ++i)
        outm[(long)(c0 + ty + i*8)*SEQ + r0 + tx] = t[tx][ty + i*8];
}

// ---------------- 128x128 tile GEMM: C = A[M,K] * Bt[N,K]^T + bias ----------------
template <bool C_F32>
__device__ __forceinline__ void gemm128x128(
    const bf16* __restrict__ A, int lda,
    const bf16* __restrict__ Bt, int ldb,
    void* __restrict__ C, int ldc,
    const float* __restrict__ bias,
    int Kdim, int m0, int n0)
{
    __shared__ __align__(16) bf16 As[128*32];
    __shared__ __align__(16) bf16 Bs[128*32];
    const int tid  = threadIdx.x;
    const int wave = tid >> 6, lane = tid & 63;
    const int lr = lane & 15, lq = lane >> 4;
    const int wrow = wave >> 1, wcol = wave & 1;
    const int sr = lane >> 2, sk = (lane & 3) * 8;

    const f32x4 zero4 = {0.f, 0.f, 0.f, 0.f};
    f32x4 acc[4][4];
#pragma unroll
    for (int i = 0; i < 4; ++i)
#pragma unroll
        for (int j = 0; j < 4; ++j) acc[i][j] = zero4;

    for (int k0 = 0; k0 < Kdim; k0 += 32) {
#pragma unroll
        for (int c = 0; c < 2; ++c) {
            const int r = wave*32 + c*16;
            async_cp16(A  + (long)(m0 + r + sr)*lda + k0 + sk, As + r*32);
            async_cp16(Bt + (long)(n0 + r + sr)*ldb + k0 + sk, Bs + r*32);
        }
        __syncthreads();
        bf16x8 af[4], bfr[4];
#pragma unroll
        for (int i = 0; i < 4; ++i)
            af[i] = *(const bf16x8*)(As + (wrow*64 + i*16 + lr)*32 + lq*8);
#pragma unroll
        for (int j = 0; j < 4; ++j)
            bfr[j] = *(const bf16x8*)(Bs + (wcol*64 + j*16 + lr)*32 + lq*8);
#pragma unroll
        for (int i = 0; i < 4; ++i)
#pragma unroll
            for (int j = 0; j < 4; ++j)
                acc[i][j] = __builtin_amdgcn_mfma_f32_16x16x32_bf16(af[i], bfr[j], acc[i][j], 0, 0, 0);
        __syncthreads();
    }
#pragma unroll
    for (int j = 0; j < 4; ++j) {
        const int col = n0 + wcol*64 + j*16 + lr;
        const float bv = bias[col];
#pragma unroll
        for (int i = 0; i < 4; ++i) {
            const int row = m0 + wrow*64 + i*16 + lq*4;
#pragma unroll
            for (int r = 0; r < 4; ++r) {
                const float v = acc[i][j][r] + bv;
                if constexpr (C_F32) ((float*)C)[(long)(row + r)*ldc + col] = v;
                else ((bf16*)C)[(long)(row + r)*ldc + col] = __float2bfloat16(v);
            }
        }
    }
}

// ---------------- QKV projection ----------------
__global__ __launch_bounds__(256) void qkv_gemm_k(
    const bf16* __restrict__ X, const bf16* __restrict__ WT3,
    const float* __restrict__ bQ, const float* __restrict__ bK, const float* __restrict__ bV,
    bf16* __restrict__ Qo, bf16* __restrict__ Ko, bf16* __restrict__ Vo)
{
    const int mt  = blockIdx.x;        // 0..31
    const int sel = blockIdx.y >> 4;   // 0=Q 1=K 2=V
    const int h   = blockIdx.y & 15;
    const float* bias; bf16* C;
    if (sel == 0)      { bias = bQ; C = Qo; }
    else if (sel == 1) { bias = bK; C = Ko; }
    else               { bias = bV; C = Vo; }
    gemm128x128<false>(X, D_MODEL, WT3 + (long)blockIdx.y*DH*D_MODEL, D_MODEL,
                       C + h*DH, NH*DH, bias + h*DH, D_MODEL, mt*128, 0);
}

// ---------------- output projection (f32 out + f32 bias) ----------------
__global__ __launch_bounds__(256) void out_gemm_k(
    const bf16* __restrict__ Z, const bf16* __restrict__ WOT,
    const float* __restrict__ bO, float* __restrict__ Out)
{
    gemm128x128<true>(Z, D_MODEL, WOT, D_MODEL, Out, D_MODEL, bO, D_MODEL,
                      (int)blockIdx.x*128, (int)blockIdx.y*128);
}

// ---------------- flash attention: S^T = K Q^T, O^T = V^T P^T ----------------
// K tile: Ks[key][128feat], 256B rows, 16B-slot XOR swizzle (slot ^= key&7).
// V tile: Vts[feat][64key], 128B rows, 16B-slot XOR swizzle (slot ^= feat&7).
// Swizzle on the per-lane GLOBAL source addr (global_load_lds writes linearly,
// rule #21) + on the ds_read addr. 2-phase pipeline (T3 minimum recipe):
// STAGE(next tile, other buffer) issued BEFORE compute(cur); single
// vmcnt(0)+barrier per tile at the end hides the global->LDS latency
// under the 32 MFMAs + softmax of the current tile.
__global__ __launch_bounds__(256) void flash_k(
    const bf16* __restrict__ Q, const bf16* __restrict__ K,
    const bf16* __restrict__ VT, bf16* __restrict__ Z)
{
    __shared__ __align__(16) bf16 Ks[2*64*128];    // [buf][key][feat] swizzled  32KB
    __shared__ __align__(16) bf16 Vts[2*128*64];   // [buf][feat][key] swizzled  32KB
    __shared__ __align__(16) bf16 Ps[64*72];       // [qrow][key] pad 72          9KB

    const int qt = (int)(gridDim.x - 1) - (int)blockIdx.x;   // big tiles dispatch first
    const int bh = blockIdx.y;
    const int b  = bh >> 4, h = bh & 15;
    const long base = (long)b*SEQ*D_MODEL + h*DH;
    const bf16* Qb  = Q + base;
    const bf16* Kb  = K + base;
    const bf16* VTb = VT + (long)bh*DH*SEQ;      // [feat][key] stride SEQ
    bf16* Zb = Z + base;
    const int q0 = qt*64;
    const int tid = threadIdx.x, wave = tid >> 6, lane = tid & 63;
    const int lr = lane & 15, lq = lane >> 4;
    const int rx = lr & 7;                        // read-side swizzle key (row&7)

    // staging geometry (wave-uniform LDS base, per-lane swizzled global src)
    const int ks_key_off = lane >> 4;             // key within 4-row chunk
    const int ks_slot    = lane & 15;             // 16B slot within 256B row
    const int vt_row_off = lane >> 3;             // feat within 8-row chunk
    const int vt_slot    = lane & 7;              // 16B slot within 128B row

    // Q B-frags in registers: lane holds q-row (q0+wave*16+lr), feats ks*32+lq*8..+8
    bf16x8 aq[4];
#pragma unroll
    for (int ks = 0; ks < 4; ++ks)
        aq[ks] = *(const bf16x8*)(Qb + (long)(q0 + wave*16 + lr)*D_MODEL + ks*32 + lq*8);

    const f32x4 zero4 = {0.f, 0.f, 0.f, 0.f};
    f32x4 o_acc[8];           // O^T: col=qrow(lr), row=feat(jf*16+lq*4+r)
#pragma unroll
    for (int jf = 0; jf < 8; ++jf) o_acc[jf] = zero4;
    float m_run = -1e30f, l_run = 0.f;   // per-lane (qrow=lr), scaled domain

    const float scale = 0.08838834764831845f;  // 1/sqrt(128)

    // issue next-tile K/V stage into buffer bases Kd/Vd (wave-uniform dests)
    auto STAGE = [&](int k0, bf16* Kd, bf16* Vd) {
#pragma unroll
        for (int c = 0; c < 4; ++c) {
            const int key = (wave*4 + c)*4 + ks_key_off;
            async_cp16(Kb + (long)(k0 + key)*D_MODEL + ((ks_slot ^ (key & 7)) * 8),
                       Kd + (wave*4 + c)*512);
        }
#pragma unroll
        for (int c = 0; c < 4; ++c) {
            const int f = (wave*4 + c)*8 + vt_row_off;
            async_cp16(VTb + (long)f*SEQ + k0 + ((vt_slot ^ (f & 7)) * 8),
                       Vd + (wave*4 + c)*512);
        }
    };

    // prologue: stage tile 0, drain, sync
    STAGE(0, Ks, Vts);
    __syncthreads();   // compiler emits s_waitcnt vmcnt(0) before s_barrier
    int cur = 0;

    for (int kt = 0; kt <= qt; ++kt) {
        bf16* Kc = Ks  + cur*(64*128);
        bf16* Vc = Vts + cur*(128*64);
        // issue NEXT tile's loads into the other buffer (latency hides under compute)
        if (kt < qt)
            STAGE((kt+1)*64, Ks + (cur^1)*(64*128), Vts + (cur^1)*(128*64));

        // S^T = K Q^T: sc[mt] C-frag: col=qrow(lr), row=key(mt*16+lq*4+r)
        f32x4 sc[4];
#pragma unroll
        for (int mt = 0; mt < 4; ++mt) sc[mt] = zero4;
        __builtin_amdgcn_s_setprio(1);
#pragma unroll
        for (int mt = 0; mt < 4; ++mt)
#pragma unroll
            for (int ks = 0; ks < 4; ++ks) {
                // logical slot = ks*4+lq, physical = slot ^ (key&7); key&7 == lr&7
                bf16x8 bk = *(const bf16x8*)(Kc + (mt*16 + lr)*128 + (((ks*4 + lq) ^ rx) * 8));
                sc[mt] = __builtin_amdgcn_mfma_f32_16x16x32_bf16(bk, aq[ks], sc[mt], 0, 0, 0);
            }
        __builtin_amdgcn_s_setprio(0);

        // causal mask: only the diagonal tile is partial
        if (kt == qt) {
            const int qrl = wave*16 + lr;   // lane's q-row within the 64-tile (q0==k0)
#pragma unroll
            for (int mt = 0; mt < 4; ++mt)
#pragma unroll
                for (int r = 0; r < 4; ++r)
                    if (mt*16 + lq*4 + r > qrl) sc[mt][r] = -1e30f;
        }

        // row max over lane's 16 keys, then across lq groups (xor 16,32)
        float mx = sc[0][0];
#pragma unroll
        for (int mt = 0; mt < 4; ++mt)
#pragma unroll
            for (int r = 0; r < 4; ++r) mx = fmaxf(mx, sc[mt][r]);
        mx = fmaxf(mx, __shfl_xor(mx, 16, 64));
        mx = fmaxf(mx, __shfl_xor(mx, 32, 64));
        mx *= scale;   // scaled domain

        // T13 defer-max: skip the O-rescale while max growth <= 8 (P bounded by e^8)
        if (!__all(mx - m_run <= 8.0f)) {
            const float mn = fmaxf(m_run, mx);
            const float al = __expf(m_run - mn);
            l_run *= al;
#pragma unroll
            for (int jf = 0; jf < 8; ++jf)
#pragma unroll
                for (int r = 0; r < 4; ++r) o_acc[jf][r] *= al;
            m_run = mn;
        }

        float rs = 0.f;
#pragma unroll
        for (int mt = 0; mt < 4; ++mt)
#pragma unroll
            for (int r = 0; r < 4; ++r) {
                const float p = __expf(fmaf(sc[mt][r], scale, -m_run));
                sc[mt][r] = p;
                rs += p;
            }
        rs += __shfl_xor(rs, 16, 64);
        rs += __shfl_xor(rs, 32, 64);
        l_run += rs;

        // P^T: C-frag (qrow=lr, key=mt*16+lq*4+r) -> Ps[qrow][key] -> contiguous B-frag
        // rows are wave-private (qrow = wave*16+lr); same-wave write->read, no barrier
        // packed 8B stores: 4 ds_write_b64 instead of 16 ds_write_b16
#pragma unroll
        for (int mt = 0; mt < 4; ++mt) {
            bf16x4 pk;
#pragma unroll
            for (int r = 0; r < 4; ++r) pk[r] = bf16bits(sc[mt][r]);
            *(bf16x4*)(Ps + (wave*16 + lr)*72 + mt*16 + lq*4) = pk;
        }

        bf16x8 pb0 = *(const bf16x8*)(Ps + (wave*16 + lr)*72 + lq*8);
        bf16x8 pb1 = *(const bf16x8*)(Ps + (wave*16 + lr)*72 + 32 + lq*8);

        // O^T += V^T P^T
        __builtin_amdgcn_s_setprio(1);
#pragma unroll
        for (int jf = 0; jf < 8; ++jf) {
            const int f = jf*16 + lr;
            bf16x8 av0 = *(const bf16x8*)(Vc + f*64 + ((lq ^ rx) * 8));
            bf16x8 av1 = *(const bf16x8*)(Vc + f*64 + (((4 + lq) ^ rx) * 8));
            o_acc[jf] = __builtin_amdgcn_mfma_f32_16x16x32_bf16(av0, pb0, o_acc[jf], 0, 0, 0);
            o_acc[jf] = __builtin_amdgcn_mfma_f32_16x16x32_bf16(av1, pb1, o_acc[jf], 0, 0, 0);
        }
        __builtin_amdgcn_s_setprio(0);

        // single barrier/tile: drains next-tile stage (vmcnt 0) AND protects
        // the buffer we just read from being overwritten next iteration
        if (kt < qt) __syncthreads();
        cur ^= 1;
    }

    const float inv = 1.f / l_run;
    const long zrow = (long)(q0 + wave*16 + lr) * D_MODEL;
#pragma unroll
    for (int jf = 0; jf < 8; ++jf) {
        bf16x4 pk;
#pragma unroll
        for (int r = 0; r < 4; ++r) pk[r] = bf16bits(o_acc[jf][r] * inv);
        *(bf16x4*)(Zb + zrow + jf*16 + lq*4) = pk;
    }
}

extern "C" void kernel_launch(void* const* d_in, const int* in_sizes, int n_in,
                              void* d_out, int out_size, void* d_ws, size_t ws_size,
                              hipStream_t stream) {
    const float* X  = (const float*)d_in[0];
    const float* WQ = (const float*)d_in[1];   // [NH][D_MODEL][DH] f32
    const float* WK = (const float*)d_in[2];
    const float* WV = (const float*)d_in[3];
    const float* WO = (const float*)d_in[4];   // flat [2048][2048] f32
    const float* bQ = (const float*)d_in[5];
    const float* bK = (const float*)d_in[6];
    const float* bV = (const float*)d_in[7];
    const float* bO = (const float*)d_in[8];
    float* out = (float*)d_out;

    bf16* ws = (bf16*)d_ws;
    const long WSZ = (long)NH*DH*D_MODEL;   // 4,194,304 elems (8 MiB bf16)
    const long MSZ = (long)MTOT*D_MODEL;    // 8,388,608 elems (16 MiB bf16)
    bf16* Xb  = ws;
    bf16* WT3 = Xb + MSZ;        // 3*WSZ: transposed QKV weights [48][DH][D_MODEL]
    bf16* WOT = WT3 + 3*WSZ;
    bf16* Qb  = WOT + WSZ;
    bf16* Kb  = Qb + MSZ;
    bf16* Vb  = Kb + MSZ;
    bf16* Zb  = Xb;              // alias: X dead after QKV GEMM
    bf16* VT  = WT3;             // alias: QKV weight transposes dead after QKV GEMM
    // ws use: MSZ + 4*WSZ + 3*MSZ = 96 MiB

    cvt_k<<<MSZ/(256*8), 256, 0, stream>>>(X, Xb);
    transpose_cvt3_k<<<dim3(DH/32, D_MODEL/32, 3*NH), 256, 0, stream>>>(
        WQ, WK, WV, WT3, D_MODEL, DH, NH);
    transpose_cvt3_k<<<dim3(D_MODEL/32, D_MODEL/32, 1), 256, 0, stream>>>(
        WO, WO, WO, WOT, D_MODEL, D_MODEL, 1);

    qkv_gemm_k<<<dim3(MTOT/128, 48), 256, 0, stream>>>(Xb, WT3, bQ, bK, bV, Qb, Kb, Vb);
    transpose_v_k<<<dim3(SEQ/32, DH/32, BATCH*NH), 256, 0, stream>>>(Vb, VT);
    flash_k<<<dim3(SEQ/64, BATCH*NH), 256, 0, stream>>>(Qb, Kb, VT, Zb);
    out_gemm_k<<<dim3(MTOT/128, D_MODEL/128), 256, 0, stream>>>(Zb, WOT, bO, out);
}

// Round 3
// 407.889 us; speedup vs baseline: 1.1259x; 1.0818x over previous
//
#include <hip/hip_runtime.h>
#include <hip/hip_bf16.h>

typedef __hip_bfloat16 bf16;
typedef __attribute__((ext_vector_type(8))) short bf16x8;  // 8 bf16 = 4 VGPRs (MFMA A/B frag)
typedef __attribute__((ext_vector_type(4))) short bf16x4;  // 4 bf16 = 8B packed store
typedef __attribute__((ext_vector_type(4))) float f32x4;   // MFMA C/D frag

#define D_MODEL 2048
#define SEQ     2048
#define NH      16
#define DH      128
#define BATCH   2
#define MTOT    (BATCH*SEQ)   // 4096

__device__ __forceinline__ void async_cp16(const bf16* g, bf16* l) {
    // wave-uniform LDS base; HW scatters lane i at base + i*16B
    __builtin_amdgcn_global_load_lds(
        (const __attribute__((address_space(1))) void*)g,
        (__attribute__((address_space(3))) void*)l, 16, 0, 0);
}

__device__ __forceinline__ short bf16bits(float f) {
    bf16 b = __float2bfloat16(f);
    return *reinterpret_cast<short*>(&b);
}

// ---------------- f32 -> bf16 elementwise convert (8 elems/thread) ----------------
__global__ __launch_bounds__(256) void cvt_k(const float* __restrict__ in,
                                             bf16* __restrict__ out) {
    const long i = ((long)blockIdx.x * 256 + threadIdx.x) * 8;
    float4 a = *(const float4*)(in + i);
    float4 b = *(const float4*)(in + i + 4);
    __align__(16) bf16 t[8];
    t[0] = __float2bfloat16(a.x); t[1] = __float2bfloat16(a.y);
    t[2] = __float2bfloat16(a.z); t[3] = __float2bfloat16(a.w);
    t[4] = __float2bfloat16(b.x); t[5] = __float2bfloat16(b.y);
    t[6] = __float2bfloat16(b.z); t[7] = __float2bfloat16(b.w);
    *(bf16x8*)(out + i) = *(const bf16x8*)t;
}

// ---- f32 [mat][R][Cn] -> bf16 [mat][Cn][R] transpose-convert; 3-src variant for QKV ----
__global__ __launch_bounds__(256) void transpose_cvt3_k(
    const float* __restrict__ in0, const float* __restrict__ in1,
    const float* __restrict__ in2,
    bf16* __restrict__ out, int R, int Cn, int mats_per_src)
{
    __shared__ float t[32][33];
    const int z = blockIdx.z;
    const int src = z / mats_per_src, mat = z % mats_per_src;
    const float* in = (src == 0) ? in0 : (src == 1) ? in1 : in2;
    const float* inm = in + (long)mat * R * Cn;
    bf16* outm = out + (long)z * R * Cn;
    const int c0 = blockIdx.x * 32, r0 = blockIdx.y * 32;
    const int tx = threadIdx.x & 31, ty = threadIdx.x >> 5;   // ty 0..7
#pragma unroll
    for (int i = 0; i < 4; ++i)
        t[ty + i*8][tx] = inm[(long)(r0 + ty + i*8) * Cn + c0 + tx];
    __syncthreads();
#pragma unroll
    for (int i = 0; i < 4; ++i)
        outm[(long)(c0 + ty + i*8) * R + r0 + tx] = __float2bfloat16(t[tx][ty + i*8]);
}

// ---------------- per-head V transpose: [b][key][h*DH+f] -> [(b,h)][f][key] bf16 ----------------
__global__ __launch_bounds__(256) void transpose_v_k(
    const bf16* __restrict__ V, bf16* __restrict__ VT)
{
    __shared__ bf16 t[32][33];
    const int bh = blockIdx.z;              // b*NH + h
    const int b = bh >> 4, h = bh & 15;
    const bf16* inm = V + (long)b*SEQ*D_MODEL + h*DH;       // [key][f] stride D_MODEL
    bf16* outm = VT + (long)bh*DH*SEQ;                      // [f][key] stride SEQ
    const int r0 = blockIdx.x * 32;         // key tile
    const int c0 = blockIdx.y * 32;         // feat tile
    const int tx = threadIdx.x & 31, ty = threadIdx.x >> 5;
#pragma unroll
    for (int i = 0; i < 4; ++i)
        t[ty + i*8][tx] = inm[(long)(r0 + ty + i*8)*D_MODEL + c0 + tx];
    __syncthreads();
#pragma unroll
    for (int i = 0; i < 4; ++i)
        outm[(long)(c0 + ty + i*8)*SEQ + r0 + tx] = t[tx][ty + i*8];
}

// ---------------- 128x128 tile GEMM: C = A[M,K] * Bt[N,K]^T + bias ----------------
template <bool C_F32>
__device__ __forceinline__ void gemm128x128(
    const bf16* __restrict__ A, int lda,
    const bf16* __restrict__ Bt, int ldb,
    void* __restrict__ C, int ldc,
    const float* __restrict__ bias,
    int Kdim, int m0, int n0)
{
    __shared__ __align__(16) bf16 As[128*32];
    __shared__ __align__(16) bf16 Bs[128*32];
    const int tid  = threadIdx.x;
    const int wave = tid >> 6, lane = tid & 63;
    const int lr = lane & 15, lq = lane >> 4;
    const int wrow = wave >> 1, wcol = wave & 1;
    const int sr = lane >> 2, sk = (lane & 3) * 8;

    const f32x4 zero4 = {0.f, 0.f, 0.f, 0.f};
    f32x4 acc[4][4];
#pragma unroll
    for (int i = 0; i < 4; ++i)
#pragma unroll
        for (int j = 0; j < 4; ++j) acc[i][j] = zero4;

    for (int k0 = 0; k0 < Kdim; k0 += 32) {
#pragma unroll
        for (int c = 0; c < 2; ++c) {
            const int r = wave*32 + c*16;
            async_cp16(A  + (long)(m0 + r + sr)*lda + k0 + sk, As + r*32);
            async_cp16(Bt + (long)(n0 + r + sr)*ldb + k0 + sk, Bs + r*32);
        }
        __syncthreads();
        bf16x8 af[4], bfr[4];
#pragma unroll
        for (int i = 0; i < 4; ++i)
            af[i] = *(const bf16x8*)(As + (wrow*64 + i*16 + lr)*32 + lq*8);
#pragma unroll
        for (int j = 0; j < 4; ++j)
            bfr[j] = *(const bf16x8*)(Bs + (wcol*64 + j*16 + lr)*32 + lq*8);
#pragma unroll
        for (int i = 0; i < 4; ++i)
#pragma unroll
            for (int j = 0; j < 4; ++j)
                acc[i][j] = __builtin_amdgcn_mfma_f32_16x16x32_bf16(af[i], bfr[j], acc[i][j], 0, 0, 0);
        __syncthreads();
    }
#pragma unroll
    for (int j = 0; j < 4; ++j) {
        const int col = n0 + wcol*64 + j*16 + lr;
        const float bv = bias[col];
#pragma unroll
        for (int i = 0; i < 4; ++i) {
            const int row = m0 + wrow*64 + i*16 + lq*4;
#pragma unroll
            for (int r = 0; r < 4; ++r) {
                const float v = acc[i][j][r] + bv;
                if constexpr (C_F32) ((float*)C)[(long)(row + r)*ldc + col] = v;
                else ((bf16*)C)[(long)(row + r)*ldc + col] = __float2bfloat16(v);
            }
        }
    }
}

// ---------------- QKV projection ----------------
__global__ __launch_bounds__(256) void qkv_gemm_k(
    const bf16* __restrict__ X, const bf16* __restrict__ WT3,
    const float* __restrict__ bQ, const float* __restrict__ bK, const float* __restrict__ bV,
    bf16* __restrict__ Qo, bf16* __restrict__ Ko, bf16* __restrict__ Vo)
{
    const int mt  = blockIdx.x;        // 0..31
    const int sel = blockIdx.y >> 4;   // 0=Q 1=K 2=V
    const int h   = blockIdx.y & 15;
    const float* bias; bf16* C;
    if (sel == 0)      { bias = bQ; C = Qo; }
    else if (sel == 1) { bias = bK; C = Ko; }
    else               { bias = bV; C = Vo; }
    gemm128x128<false>(X, D_MODEL, WT3 + (long)blockIdx.y*DH*D_MODEL, D_MODEL,
                       C + h*DH, NH*DH, bias + h*DH, D_MODEL, mt*128, 0);
}

// ---------------- output projection (f32 out + f32 bias) ----------------
__global__ __launch_bounds__(256) void out_gemm_k(
    const bf16* __restrict__ Z, const bf16* __restrict__ WOT,
    const float* __restrict__ bO, float* __restrict__ Out)
{
    gemm128x128<true>(Z, D_MODEL, WOT, D_MODEL, Out, D_MODEL, bO, D_MODEL,
                      (int)blockIdx.x*128, (int)blockIdx.y*128);
}

// ---------------- flash attention: S^T = K Q^T, O^T = V^T P^T ----------------
// QBLK=128, 8 waves (512 thr), KVBLK=64, single-buffered K/V (R1/R2 A/B showed
// dbuf = no gain). Each wave owns 16 q-rows; one K/V stage + 2 barriers serve
// 128 q-rows (2x amortization vs QBLK=64) and 8 waves/block double the per-CU
// wave count so serial softmax/shfl chains overlap across waves.
// K tile: Ks[key][128feat], 256B rows, 16B-slot XOR swizzle (slot ^= key&7).
// V tile: Vts[feat][64key], 128B rows, 16B-slot XOR swizzle (slot ^= feat&7).
// Swizzle on per-lane GLOBAL src addr (global_load_lds writes linearly, rule
// #21) + on the ds_read addr.
__global__ __launch_bounds__(512) void flash_k(
    const bf16* __restrict__ Q, const bf16* __restrict__ K,
    const bf16* __restrict__ VT, bf16* __restrict__ Z)
{
    __shared__ __align__(16) bf16 Ks[64*128];    // [key][feat] swizzled  16KB
    __shared__ __align__(16) bf16 Vts[128*64];   // [feat][key] swizzled  16KB
    __shared__ __align__(16) bf16 Ps[128*72];    // [qrow][key] pad 72    18KB

    const int qt = (int)(gridDim.x - 1) - (int)blockIdx.x;   // big blocks dispatch first
    const int bh = blockIdx.y;
    const int b  = bh >> 4, h = bh & 15;
    const long base = (long)b*SEQ*D_MODEL + h*DH;
    const bf16* Qb  = Q + base;
    const bf16* Kb  = K + base;
    const bf16* VTb = VT + (long)bh*DH*SEQ;      // [feat][key] stride SEQ
    bf16* Zb = Z + base;
    const int q0 = qt*128;
    const int tid = threadIdx.x, wave = tid >> 6, lane = tid & 63;
    const int lr = lane & 15, lq = lane >> 4;
    const int rx = lr & 7;                        // read-side swizzle key (row&7)

    // staging geometry (wave-uniform LDS base, per-lane swizzled global src)
    const int ks_key_off = lane >> 4;             // key within 4-row chunk
    const int ks_slot    = lane & 15;             // 16B slot within 256B row
    const int vt_row_off = lane >> 3;             // feat within 8-row chunk
    const int vt_slot    = lane & 7;              // 16B slot within 128B row

    // Q B-frags in registers: lane holds q-row (q0+wave*16+lr), feats ks*32+lq*8..+8
    bf16x8 aq[4];
#pragma unroll
    for (int ks = 0; ks < 4; ++ks)
        aq[ks] = *(const bf16x8*)(Qb + (long)(q0 + wave*16 + lr)*D_MODEL + ks*32 + lq*8);

    const f32x4 zero4 = {0.f, 0.f, 0.f, 0.f};
    f32x4 o_acc[8];           // O^T: col=qrow(lr), row=feat(jf*16+lq*4+r)
#pragma unroll
    for (int jf = 0; jf < 8; ++jf) o_acc[jf] = zero4;
    float m_run = -1e30f, l_run = 0.f;   // per-lane (qrow=lr), scaled domain

    const float scale = 0.08838834764831845f;  // 1/sqrt(128)
    const int NT = 2*qt + 2;   // key tiles covering rows q0..q0+127

    for (int kt = 0; kt < NT; ++kt) {
        const int k0 = kt*64;
        __syncthreads();   // all waves done reading Ks/Vts of prev tile
        // stage: wave w covers K chunks {2w,2w+1} (4 keys x 256B each) and
        // V chunks {2w,2w+1} (8 feats x 128B each)
#pragma unroll
        for (int c2 = 0; c2 < 2; ++c2) {
            const int c = wave*2 + c2;
            const int key = c*4 + ks_key_off;
            async_cp16(Kb + (long)(k0 + key)*D_MODEL + ((ks_slot ^ (key & 7)) * 8),
                       Ks + c*512);
            const int f = c*8 + vt_row_off;
            async_cp16(VTb + (long)f*SEQ + k0 + ((vt_slot ^ (f & 7)) * 8),
                       Vts + c*512);
        }
        __syncthreads();   // drains vmcnt(0): tile ready

        // fully-masked wave (all 16 q-rows below this key tile)? skip compute
        const int rel_hi = q0 + wave*16 + 15 - k0;
        if (rel_hi >= 0) {
            // S^T = K Q^T: sc[mt] C-frag: col=qrow(lr), row=key(mt*16+lq*4+r)
            f32x4 sc[4];
#pragma unroll
            for (int mt = 0; mt < 4; ++mt) sc[mt] = zero4;
            __builtin_amdgcn_s_setprio(1);
#pragma unroll
            for (int mt = 0; mt < 4; ++mt)
#pragma unroll
                for (int ks = 0; ks < 4; ++ks) {
                    // logical slot = ks*4+lq, physical = slot ^ (key&7); key&7 == lr&7
                    bf16x8 bk = *(const bf16x8*)(Ks + (mt*16 + lr)*128 + (((ks*4 + lq) ^ rx) * 8));
                    sc[mt] = __builtin_amdgcn_mfma_f32_16x16x32_bf16(bk, aq[ks], sc[mt], 0, 0, 0);
                }
            __builtin_amdgcn_s_setprio(0);

            // causal mask (partial tile): key-in-tile > rel  (rel = qrow - k0)
            if (rel_hi < 78) {
                const int rel = q0 + wave*16 + lr - k0;
#pragma unroll
                for (int mt = 0; mt < 4; ++mt)
#pragma unroll
                    for (int r = 0; r < 4; ++r)
                        if (mt*16 + lq*4 + r > rel) sc[mt][r] = -1e30f;
            }

            // row max over lane's 16 keys, then across lq groups (xor 16,32)
            float mx = sc[0][0];
#pragma unroll
            for (int mt = 0; mt < 4; ++mt)
#pragma unroll
                for (int r = 0; r < 4; ++r) mx = fmaxf(mx, sc[mt][r]);
            mx = fmaxf(mx, __shfl_xor(mx, 16, 64));
            mx = fmaxf(mx, __shfl_xor(mx, 32, 64));
            mx *= scale;   // scaled domain

            // T13 defer-max: skip O-rescale while max growth <= 8 (P bounded by e^8)
            if (!__all(mx - m_run <= 8.0f)) {
                const float mn = fmaxf(m_run, mx);
                const float al = __expf(m_run - mn);
                l_run *= al;
#pragma unroll
                for (int jf = 0; jf < 8; ++jf)
#pragma unroll
                    for (int r = 0; r < 4; ++r) o_acc[jf][r] *= al;
                m_run = mn;
            }

            float rs = 0.f;
#pragma unroll
            for (int mt = 0; mt < 4; ++mt)
#pragma unroll
                for (int r = 0; r < 4; ++r) {
                    const float p = __expf(fmaf(sc[mt][r], scale, -m_run));
                    sc[mt][r] = p;
                    rs += p;
                }
            rs += __shfl_xor(rs, 16, 64);
            rs += __shfl_xor(rs, 32, 64);
            l_run += rs;

            // P^T: C-frag (qrow=lr, key=mt*16+lq*4+r) -> Ps[qrow][key] -> B-frag
            // rows are wave-private (qrow = wave*16+lr); same-wave write->read
#pragma unroll
            for (int mt = 0; mt < 4; ++mt) {
                bf16x4 pk;
#pragma unroll
                for (int r = 0; r < 4; ++r) pk[r] = bf16bits(sc[mt][r]);
                *(bf16x4*)(Ps + (wave*16 + lr)*72 + mt*16 + lq*4) = pk;
            }

            bf16x8 pb0 = *(const bf16x8*)(Ps + (wave*16 + lr)*72 + lq*8);
            bf16x8 pb1 = *(const bf16x8*)(Ps + (wave*16 + lr)*72 + 32 + lq*8);

            // O^T += V^T P^T
            __builtin_amdgcn_s_setprio(1);
#pragma unroll
            for (int jf = 0; jf < 8; ++jf) {
                const int f = jf*16 + lr;
                bf16x8 av0 = *(const bf16x8*)(Vts + f*64 + ((lq ^ rx) * 8));
                bf16x8 av1 = *(const bf16x8*)(Vts + f*64 + (((4 + lq) ^ rx) * 8));
                o_acc[jf] = __builtin_amdgcn_mfma_f32_16x16x32_bf16(av0, pb0, o_acc[jf], 0, 0, 0);
                o_acc[jf] = __builtin_amdgcn_mfma_f32_16x16x32_bf16(av1, pb1, o_acc[jf], 0, 0, 0);
            }
            __builtin_amdgcn_s_setprio(0);
        }
    }

    const float inv = 1.f / l_run;
    const long zrow = (long)(q0 + wave*16 + lr) * D_MODEL;
#pragma unroll
    for (int jf = 0; jf < 8; ++jf) {
        bf16x4 pk;
#pragma unroll
        for (int r = 0; r < 4; ++r) pk[r] = bf16bits(o_acc[jf][r] * inv);
        *(bf16x4*)(Zb + zrow + jf*16 + lq*4) = pk;
    }
}

extern "C" void kernel_launch(void* const* d_in, const int* in_sizes, int n_in,
                              void* d_out, int out_size, void* d_ws, size_t ws_size,
                              hipStream_t stream) {
    const float* X  = (const float*)d_in[0];
    const float* WQ = (const float*)d_in[1];   // [NH][D_MODEL][DH] f32
    const float* WK = (const float*)d_in[2];
    const float* WV = (const float*)d_in[3];
    const float* WO = (const float*)d_in[4];   // flat [2048][2048] f32
    const float* bQ = (const float*)d_in[5];
    const float* bK = (const float*)d_in[6];
    const float* bV = (const float*)d_in[7];
    const float* bO = (const float*)d_in[8];
    float* out = (float*)d_out;

    bf16* ws = (bf16*)d_ws;
    const long WSZ = (long)NH*DH*D_MODEL;   // 4,194,304 elems (8 MiB bf16)
    const long MSZ = (long)MTOT*D_MODEL;    // 8,388,608 elems (16 MiB bf16)
    bf16* Xb  = ws;
    bf16* WT3 = Xb + MSZ;        // 3*WSZ: transposed QKV weights [48][DH][D_MODEL]
    bf16* WOT = WT3 + 3*WSZ;
    bf16* Qb  = WOT + WSZ;
    bf16* Kb  = Qb + MSZ;
    bf16* Vb  = Kb + MSZ;
    bf16* Zb  = Xb;              // alias: X dead after QKV GEMM
    bf16* VT  = WT3;             // alias: QKV weight transposes dead after QKV GEMM
    // ws use: MSZ + 4*WSZ + 3*MSZ = 96 MiB

    cvt_k<<<MSZ/(256*8), 256, 0, stream>>>(X, Xb);
    transpose_cvt3_k<<<dim3(DH/32, D_MODEL/32, 3*NH), 256, 0, stream>>>(
        WQ, WK, WV, WT3, D_MODEL, DH, NH);
    transpose_cvt3_k<<<dim3(D_MODEL/32, D_MODEL/32, 1), 256, 0, stream>>>(
        WO, WO, WO, WOT, D_MODEL, D_MODEL, 1);

    qkv_gemm_k<<<dim3(MTOT/128, 48), 256, 0, stream>>>(Xb, WT3, bQ, bK, bV, Qb, Kb, Vb);
    transpose_v_k<<<dim3(SEQ/32, DH/32, BATCH*NH), 256, 0, stream>>>(Vb, VT);
    flash_k<<<dim3(SEQ/128, BATCH*NH), 512, 0, stream>>>(Qb, Kb, VT, Zb);
    out_gemm_k<<<dim3(MTOT/128, D_MODEL/128), 256, 0, stream>>>(Zb, WOT, bO, out);
}